// Round 3
// baseline (60.902 us; speedup 1.0000x reference)
//
#include <hip/hip_runtime.h>
#include <math.h>

#define NB    1024      // buckets (monotone map floor(d*NB) -> cross-bucket order strict)
#define NT    1024      // threads in the single workgroup
#define ITEMS 16        // supports n <= NT*ITEMS = 16384
#define L2REG 0.01f

// One workgroup does everything: W^2 reduce, exp+histogram, suffix/prefix
// scans, bucket-sorted scatter into LDS, exact same-bucket pairwise risk,
// final cox reduce + output. No workspace, no memset, single graph node.
__global__ void __launch_bounds__(NT)
cox_fused_kernel(const float* __restrict__ theta,
                 const float* __restrict__ dur,
                 const float* __restrict__ ev,
                 const float* __restrict__ W,
                 float* __restrict__ out,
                 int n, int wn) {
    __shared__ float2 memb[NT * ITEMS];   // 128 KB  bucket-sorted {d, exp(theta)}
    __shared__ float  esum[NB];           // 4 KB    bucket exp-sums -> excl suffix
    __shared__ int    pref[NB];           // 4 KB    counts -> inclusive prefix
    __shared__ int    cursor[NB];         // 4 KB    scatter cursors
    __shared__ float  red[32];            // block reduction scratch

    int t = threadIdx.x;

    // ---- W^2 partial (coalesced float4; wn = 131072 divisible by 4*NT) ----
    float w2 = 0.f;
    for (int i = t * 4; i < wn; i += NT * 4) {
        float4 w = *reinterpret_cast<const float4*>(W + i);
        w2 += w.x * w.x + w.y * w.y + w.z * w.z + w.w * w.w;
    }

    // ---- zero histogram ----
    esum[t] = 0.f;
    pref[t] = 0;
    __syncthreads();

    // ---- pass 1: load, exp, histogram (keep d,e in registers, static idx) ----
    float d[ITEMS], e[ITEMS];
    #pragma unroll
    for (int it = 0; it < ITEMS; ++it) {
        int j = t + it * NT;
        if (j < n) {
            float dj = dur[j];
            float ej = expf(theta[j]);
            d[it] = dj;
            e[it] = ej;
            int b = (int)(dj * (float)NB);
            b = b < 0 ? 0 : (b >= NB ? NB - 1 : b);
            atomicAdd(&esum[b], ej);
            atomicAdd(&pref[b], 1);
        } else {
            d[it] = -1.f;
            e[it] = 0.f;
        }
    }
    __syncthreads();

    int myc = pref[t];
    // ---- joint scans: suffix(esum), prefix(pref); in-place, 2 barriers/step ----
    for (int off = 1; off < NB; off <<= 1) {
        float a = (t + off < NB) ? esum[t + off] : 0.f;
        int   c = (t >= off)     ? pref[t - off] : 0;
        __syncthreads();
        esum[t] += a;
        pref[t] += c;
        __syncthreads();
    }
    // esum[t] now inclusive suffix -> make exclusive; cursor = excl prefix
    float sufx = (t + 1 < NB) ? esum[t + 1] : 0.f;
    int   b0   = pref[t] - myc;
    __syncthreads();
    esum[t]   = sufx;
    cursor[t] = b0;
    __syncthreads();

    // ---- scatter into bucket-sorted LDS array ----
    #pragma unroll
    for (int it = 0; it < ITEMS; ++it) {
        int j = t + it * NT;
        if (j < n) {
            float dj = d[it];
            int b = (int)(dj * (float)NB);
            b = b < 0 ? 0 : (b >= NB ? NB - 1 : b);
            int pos = atomicAdd(&cursor[b], 1);
            memb[pos] = make_float2(dj, e[it]);
        }
    }
    __syncthreads();

    // ---- pass 2: risk = excl-suffix + exact in-bucket pairwise >= ----
    float p = 0.f;
    #pragma unroll
    for (int it = 0; it < ITEMS; ++it) {
        int j = t + it * NT;
        if (j < n) {
            float dj = d[it];
            int b = (int)(dj * (float)NB);
            b = b < 0 ? 0 : (b >= NB ? NB - 1 : b);
            float risk = esum[b];                  // sum over strictly-higher buckets
            int kb = (b > 0) ? pref[b - 1] : 0;
            int ke = pref[b];
            for (int k = kb; k < ke; ++k) {
                float2 m = memb[k];
                risk += (m.x >= dj) ? m.y : 0.f;   // exact tie semantics
            }
            p += (theta[j] - logf(risk)) * ev[j];  // risk >= exp(theta_j) > 0
        }
    }

    // ---- block reduce p (cox sum) and w2; write scalar ----
    for (int off = 32; off > 0; off >>= 1) {
        p  += __shfl_down(p,  off, 64);
        w2 += __shfl_down(w2, off, 64);
    }
    int wid = t >> 6, lane = t & 63;
    if (lane == 0) { red[wid] = p; red[wid + 16] = w2; }
    __syncthreads();
    if (t == 0) {
        float ps = 0.f, ws = 0.f;
        #pragma unroll
        for (int k = 0; k < NT / 64; ++k) { ps += red[k]; ws += red[k + 16]; }
        out[0] = -ps / (float)n + L2REG * sqrtf(ws);
    }
}

extern "C" void kernel_launch(void* const* d_in, const int* in_sizes, int n_in,
                              void* d_out, int out_size, void* d_ws, size_t ws_size,
                              hipStream_t stream) {
    const float* hazard = (const float*)d_in[0];  // [n,1]
    const float* dur    = (const float*)d_in[1];  // [n]
    const float* ev     = (const float*)d_in[2];  // [n]
    const float* W      = (const float*)d_in[3];  // [512*256]
    int n  = in_sizes[1];                          // 16384 (<= NT*ITEMS)
    int wn = in_sizes[3];

    cox_fused_kernel<<<1, NT, 0, stream>>>(hazard, dur, ev, W,
                                           (float*)d_out, n, wn);
}